// Round 2
// baseline (589.015 us; speedup 1.0000x reference)
//
#include <hip/hip_runtime.h>
#include <hip/hip_bf16.h>

#define H 768
#define NH 12
#define DH 64
#define NNODES 2048
#define NEDGES 131072

typedef __bf16 bf16x8 __attribute__((ext_vector_type(8)));
typedef float floatx4 __attribute__((ext_vector_type(4)));

// direct global->LDS DMA, 16B per lane (dest must be wave-uniform base + lane*16)
#define GLOAD_LDS16(gptr, ldsptr)                                                        \
  __builtin_amdgcn_global_load_lds((const __attribute__((address_space(1))) void*)(gptr), \
                                   (__attribute__((address_space(3))) void*)(ldsptr),     \
                                   16, 0, 0)

__device__ __forceinline__ unsigned short f2bf(float x) {
  union { __hip_bfloat16 h; unsigned short u; } cv;
  cv.h = __float2bfloat16(x);
  return cv.u;
}

// ---------------- fp32 -> bf16 conversion (vectorized x4) + denom zero ------
__global__ __launch_bounds__(256)
void convert_kernel(const float* __restrict__ hs,
                    const float* __restrict__ Wq,
                    const float* __restrict__ Wk,
                    const float* __restrict__ Wv,
                    __hip_bfloat16* __restrict__ hsb,
                    __hip_bfloat16* __restrict__ wb,
                    float* __restrict__ denom) {
  int i = blockIdx.x * 256 + threadIdx.x;
  const int n_hs4 = NNODES * H / 4;   // 393216
  const int n_w4  = H * H / 4;        // 147456
  if (i < n_hs4) {
    float4 v = ((const float4*)hs)[i];
    ((ushort4*)hsb)[i] = make_ushort4(f2bf(v.x), f2bf(v.y), f2bf(v.z), f2bf(v.w));
    return;
  }
  int j = i - n_hs4;
  if (j < 3 * n_w4) {
    const float* src = (j < n_w4) ? Wq : (j < 2 * n_w4 ? Wk : Wv);
    float4 v = ((const float4*)src)[j % n_w4];
    ((ushort4*)wb)[j] = make_ushort4(f2bf(v.x), f2bf(v.y), f2bf(v.z), f2bf(v.w));
    return;
  }
  int z = j - 3 * n_w4;
  if (z < NNODES * NH / 4) {          // 6144 float4 = 24576 floats
    ((float4*)denom)[z] = make_float4(0.f, 0.f, 0.f, 0.f);
  }
}

// ---------------- QKV projection GEMM: C = A * W^T + bias -------------------
__global__ __launch_bounds__(256)
void qkv_gemm(const __hip_bfloat16* __restrict__ A,
              const __hip_bfloat16* __restrict__ Wb,
              const float* __restrict__ b0,
              const float* __restrict__ b1,
              const float* __restrict__ b2,
              float* __restrict__ out) {
  __shared__ __hip_bfloat16 As[128][32];
  __shared__ __hip_bfloat16 Bs[128][32];

  const int t    = threadIdx.x;
  const int wave = t >> 6;
  const int lane = t & 63;
  const int bm   = blockIdx.x * 128;
  const int bn   = blockIdx.y * 128;
  const int mat  = blockIdx.z;

  const __hip_bfloat16* B = Wb + (size_t)mat * H * H;
  const float* bias = (mat == 0) ? b0 : ((mat == 1) ? b1 : b2);
  float* C = out + (size_t)mat * NNODES * H;

  const int wm = (wave & 1) * 64;
  const int wn = (wave >> 1) * 64;
  const int lr = lane & 15;
  const int lq = lane >> 4;

  floatx4 acc[4][4] = {};

  const int ar = t >> 2;
  const int ac = (t & 3) * 8;
  __hip_bfloat16* AsF = &As[0][0];
  __hip_bfloat16* BsF = &Bs[0][0];

  for (int kt = 0; kt < H; kt += 32) {
    GLOAD_LDS16(A + (size_t)(bm + ar) * H + kt + ac,      AsF + t * 8);
    GLOAD_LDS16(A + (size_t)(bm + 64 + ar) * H + kt + ac, AsF + 64 * 32 + t * 8);
    GLOAD_LDS16(B + (size_t)(bn + ar) * H + kt + ac,      BsF + t * 8);
    GLOAD_LDS16(B + (size_t)(bn + 64 + ar) * H + kt + ac, BsF + 64 * 32 + t * 8);
    __syncthreads();

    bf16x8 af[4], bfr[4];
#pragma unroll
    for (int i = 0; i < 4; i++)
      af[i] = *(const bf16x8*)&As[wm + i * 16 + lr][lq * 8];
#pragma unroll
    for (int i = 0; i < 4; i++)
      bfr[i] = *(const bf16x8*)&Bs[wn + i * 16 + lr][lq * 8];
#pragma unroll
    for (int mi = 0; mi < 4; mi++)
#pragma unroll
      for (int ni = 0; ni < 4; ni++)
        acc[mi][ni] = __builtin_amdgcn_mfma_f32_16x16x32_bf16(
            af[mi], bfr[ni], acc[mi][ni], 0, 0, 0);
    __syncthreads();
  }

#pragma unroll
  for (int ni = 0; ni < 4; ni++) {
    int col = bn + wn + ni * 16 + lr;
    float bv = bias[col];
#pragma unroll
    for (int mi = 0; mi < 4; mi++) {
#pragma unroll
      for (int r = 0; r < 4; r++) {
        int row = bm + wm + mi * 16 + lq * 4 + r;
        C[(size_t)row * H + col] = acc[mi][ni][r] + bv;
      }
    }
  }
}

// ---------------- repack Q,K fp32 [N][H] -> per-head bf16 [NH][N][DH] -------
// Q is pre-scaled by 1/sqrt(DH) = 0.125 so S and Qrel carry the softmax scale.
__global__ __launch_bounds__(256)
void repack_kernel(const float* __restrict__ Q, const float* __restrict__ K,
                   __hip_bfloat16* __restrict__ Qh, __hip_bfloat16* __restrict__ Kh) {
  int tid = blockIdx.x * 256 + threadIdx.x;   // < 393216
  int d4 = tid & 15;                           // d = d4*4
  int th = tid >> 4;                           // 0..24575
  int h  = th % NH;
  int t  = th / NH;
  size_t in_off  = (size_t)t * H + h * DH + d4 * 4;
  size_t out_off = ((size_t)h * NNODES + t) * DH + d4 * 4;
  float4 q4 = *(const float4*)(Q + in_off);
  float4 k4 = *(const float4*)(K + in_off);
  *(ushort4*)((unsigned short*)Qh + out_off) =
      make_ushort4(f2bf(q4.x * 0.125f), f2bf(q4.y * 0.125f),
                   f2bf(q4.z * 0.125f), f2bf(q4.w * 0.125f));
  *(ushort4*)((unsigned short*)Kh + out_off) =
      make_ushort4(f2bf(k4.x), f2bf(k4.y), f2bf(k4.z), f2bf(k4.w));
}

// ---------------- Qrel[t][p][h] = 0.125 * Q[t,h,:].relk[p,:] ---------------
__global__ __launch_bounds__(256)
void qrel_kernel(const float* __restrict__ Q, const float* __restrict__ relk,
                 float* __restrict__ qrel) {
  int t = blockIdx.x;
  int tid = threadIdx.x;
  if (tid >= 16 * NH) return;                 // 192 active
  int h = tid % NH;
  int p = tid / NH;
  const float* q = Q + (size_t)t * H + h * DH;
  const float* r = relk + p * DH;
  float s = 0.f;
#pragma unroll 8
  for (int d = 0; d < DH; d++) s += q[d] * r[d];
  qrel[((size_t)t * 16 + p) * NH + h] = s * 0.125f;
}

// ---------------- dense per-head score matrices: S[h] = Qh[h] . Kh[h]^T -----
// M = N = 2048, K = 64, bf16 MFMA, nontemporal fp32 out (read-once stream)
__global__ __launch_bounds__(256)
void sgemm_kernel(const __hip_bfloat16* __restrict__ Qh,
                  const __hip_bfloat16* __restrict__ Kh,
                  float* __restrict__ S) {
  __shared__ __hip_bfloat16 As[128][32];
  __shared__ __hip_bfloat16 Bs[128][32];

  const int t    = threadIdx.x;
  const int wave = t >> 6;
  const int lane = t & 63;
  const int bm   = blockIdx.x * 128;
  const int bn   = blockIdx.y * 128;
  const int h    = blockIdx.z;

  const __hip_bfloat16* A = Qh + (size_t)h * NNODES * DH;
  const __hip_bfloat16* B = Kh + (size_t)h * NNODES * DH;
  float* C = S + (size_t)h * NNODES * NNODES;

  const int wm = (wave & 1) * 64;
  const int wn = (wave >> 1) * 64;
  const int lr = lane & 15;
  const int lq = lane >> 4;

  floatx4 acc[4][4] = {};

  const int ar = t >> 2;
  const int ac = (t & 3) * 8;
  __hip_bfloat16* AsF = &As[0][0];
  __hip_bfloat16* BsF = &Bs[0][0];

  for (int kt = 0; kt < DH; kt += 32) {
    GLOAD_LDS16(A + (size_t)(bm + ar) * DH + kt + ac,      AsF + t * 8);
    GLOAD_LDS16(A + (size_t)(bm + 64 + ar) * DH + kt + ac, AsF + 64 * 32 + t * 8);
    GLOAD_LDS16(B + (size_t)(bn + ar) * DH + kt + ac,      BsF + t * 8);
    GLOAD_LDS16(B + (size_t)(bn + 64 + ar) * DH + kt + ac, BsF + 64 * 32 + t * 8);
    __syncthreads();

    bf16x8 af[4], bfr[4];
#pragma unroll
    for (int i = 0; i < 4; i++)
      af[i] = *(const bf16x8*)&As[wm + i * 16 + lr][lq * 8];
#pragma unroll
    for (int i = 0; i < 4; i++)
      bfr[i] = *(const bf16x8*)&Bs[wn + i * 16 + lr][lq * 8];
#pragma unroll
    for (int mi = 0; mi < 4; mi++)
#pragma unroll
      for (int ni = 0; ni < 4; ni++)
        acc[mi][ni] = __builtin_amdgcn_mfma_f32_16x16x32_bf16(
            af[mi], bfr[ni], acc[mi][ni], 0, 0, 0);
    __syncthreads();
  }

#pragma unroll
  for (int ni = 0; ni < 4; ni++) {
    int col = bn + wn + ni * 16 + lr;
#pragma unroll
    for (int mi = 0; mi < 4; mi++) {
#pragma unroll
      for (int r = 0; r < 4; r++) {
        int row = bm + wm + mi * 16 + lq * 4 + r;
        __builtin_nontemporal_store(acc[mi][ni][r],
                                    C + (size_t)row * NNODES + col);
      }
    }
  }
}

// ---------------- scores from dense S: 12 x 4B gathers per edge -------------
__global__ __launch_bounds__(256)
void scores2_kernel(const float* __restrict__ S, const float* __restrict__ qrel,
                    const int* __restrict__ esrc, const int* __restrict__ etgt,
                    const int* __restrict__ epos,
                    float* __restrict__ scores, float* __restrict__ denom) {
  int tid = blockIdx.x * 256 + threadIdx.x;
  int e = tid >> 4;
  int h = tid & 15;
  int src = esrc[e], tgt = etgt[e], pos = epos[e];   // broadcast in 16-lane group
  if (h < NH) {
    float s = S[(size_t)h * NNODES * NNODES + (size_t)tgt * NNODES + src]
            + qrel[((size_t)tgt * 16 + pos) * NH + h];
    float sc = __expf(s);      // scale already folded into S and qrel
    scores[(size_t)e * NH + h] = sc;
    atomicAdd(denom + (size_t)tgt * NH + h, sc);
  }
}

// ---------------- fallback: per-edge scores via row gather ------------------
__global__ __launch_bounds__(256)
void scores_kernel(const float* __restrict__ Q, const float* __restrict__ K,
                   const float* __restrict__ relk,
                   const int* __restrict__ esrc, const int* __restrict__ etgt,
                   const int* __restrict__ epos,
                   float* __restrict__ scores, float* __restrict__ denom) {
  const int wave = threadIdx.x >> 6;
  const int lane = threadIdx.x & 63;
  const int e = blockIdx.x * 4 + wave;
  const int src = esrc[e], tgt = etgt[e], pos = epos[e];
  const int g = lane >> 4;
  const int off = (lane & 15) * 4;

  const float4 r4 = *(const float4*)(relk + pos * DH + off);
  float s[3];
#pragma unroll
  for (int c = 0; c < 3; c++) {
    const float4 q4 = *(const float4*)(Q + (size_t)tgt * H + c * 256 + lane * 4);
    const float4 k4 = *(const float4*)(K + (size_t)src * H + c * 256 + lane * 4);
    s[c] = q4.x * (k4.x + r4.x) + q4.y * (k4.y + r4.y) +
           q4.z * (k4.z + r4.z) + q4.w * (k4.w + r4.w);
  }
#pragma unroll
  for (int m = 1; m < 16; m <<= 1) {
    s[0] += __shfl_xor(s[0], m);
    s[1] += __shfl_xor(s[1], m);
    s[2] += __shfl_xor(s[2], m);
  }
  if ((lane & 15) == 0) {
#pragma unroll
    for (int c = 0; c < 3; c++) {
      float sc = __expf(s[c] * 0.125f);
      int h = c * 4 + g;
      scores[(size_t)e * NH + h] = sc;
      atomicAdd(denom + (size_t)tgt * NH + h, sc);
    }
  }
}

// ---------------- per-edge weighted values ----------------------------------
__global__ __launch_bounds__(256)
void weighted_kernel(const float* __restrict__ V, const float* __restrict__ relv,
                     const int* __restrict__ esrc, const int* __restrict__ etgt,
                     const int* __restrict__ epos,
                     const float* __restrict__ scores,
                     const float* __restrict__ denom,
                     float* __restrict__ out) {
  const int wave = threadIdx.x >> 6;
  const int lane = threadIdx.x & 63;
  const int e = blockIdx.x * 4 + wave;
  const int src = esrc[e], tgt = etgt[e], pos = epos[e];
  const int g = lane >> 4;
  const int off = (lane & 15) * 4;

  const float4 r4 = *(const float4*)(relv + pos * DH + off);
#pragma unroll
  for (int c = 0; c < 3; c++) {
    int h = c * 4 + g;
    float a = scores[(size_t)e * NH + h] / denom[(size_t)tgt * NH + h];
    float4 v4 = *(const float4*)(V + (size_t)src * H + c * 256 + lane * 4);
    floatx4 o;
    o.x = (v4.x + r4.x) * a;
    o.y = (v4.y + r4.y) * a;
    o.z = (v4.z + r4.z) * a;
    o.w = (v4.w + r4.w) * a;
    __builtin_nontemporal_store(o, (floatx4*)(out + (size_t)e * H + c * 256 + lane * 4));
  }
}

extern "C" void kernel_launch(void* const* d_in, const int* in_sizes, int n_in,
                              void* d_out, int out_size, void* d_ws, size_t ws_size,
                              hipStream_t stream) {
  const float* hs   = (const float*)d_in[0];
  const float* Wq   = (const float*)d_in[1];
  const float* bq   = (const float*)d_in[2];
  const float* Wk   = (const float*)d_in[3];
  const float* bk   = (const float*)d_in[4];
  const float* Wv   = (const float*)d_in[5];
  const float* bv   = (const float*)d_in[6];
  const float* relk = (const float*)d_in[7];
  const float* relv = (const float*)d_in[8];
  const int* esrc   = (const int*)d_in[9];
  const int* etgt   = (const int*)d_in[10];
  const int* epos   = (const int*)d_in[12];
  float* out = (float*)d_out;

  char* ws = (char*)d_ws;
  __hip_bfloat16* hsb = (__hip_bfloat16*)ws;                       //  3,145,728 B
  __hip_bfloat16* wb  = (__hip_bfloat16*)(ws + 3145728);           //  3,538,944 B
  float* qkv    = (float*)(ws + 6684672);                          // 18,874,368 B
  float* scores = (float*)(ws + 25559040);                         //  6,291,456 B
  float* denom  = (float*)(ws + 31850496);                         //     98,304 B
  __hip_bfloat16* Qh = (__hip_bfloat16*)(ws + 31948800);           //  3,145,728 B
  __hip_bfloat16* Kh = (__hip_bfloat16*)(ws + 35094528);           //  3,145,728 B
  float* qrel   = (float*)(ws + 38240256);                         //  1,572,864 B
  float* Sm     = (float*)(ws + 39813120);                         // 201,326,592 B
  const size_t WS_NEED = 241139712ULL;

  // 1) convert hs + weights to bf16 + zero denom
  convert_kernel<<<3288, 256, 0, stream>>>(hs, Wq, Wk, Wv, hsb, wb, denom);

  // 2) QKV projection
  dim3 grid_gemm(16, 6, 3);
  qkv_gemm<<<grid_gemm, 256, 0, stream>>>(hsb, wb, bq, bk, bv, qkv);

  const float* Qp = qkv;
  const float* Kp = qkv + (size_t)NNODES * H;
  const float* Vp = qkv + (size_t)2 * NNODES * H;

  if (ws_size >= WS_NEED) {
    // 3) per-head bf16 repack (Q pre-scaled by 0.125)
    repack_kernel<<<1536, 256, 0, stream>>>(Qp, Kp, Qh, Kh);
    // 4) Qrel table
    qrel_kernel<<<NNODES, 256, 0, stream>>>(Qp, relk, qrel);
    // 5) dense per-head score matrices (MFMA, nt-stream 201 MB)
    dim3 grid_s(16, 16, NH);
    sgemm_kernel<<<grid_s, 256, 0, stream>>>(Qh, Kh, Sm);
    // 6) per-edge exp-scores from dense S + denom scatter-add
    scores2_kernel<<<NEDGES * 16 / 256, 256, 0, stream>>>(Sm, qrel, esrc, etgt,
                                                          epos, scores, denom);
  } else {
    // fallback: row-gather scores (workspace too small for dense S)
    scores_kernel<<<NEDGES / 4, 256, 0, stream>>>(Qp, Kp, relk, esrc, etgt, epos,
                                                  scores, denom);
  }

  // 7) per-edge weighted values -> out (nontemporal)
  weighted_kernel<<<NEDGES / 4, 256, 0, stream>>>(Vp, relv, esrc, etgt, epos,
                                                  scores, denom, out);
}

// Round 4
// 537.293 us; speedup vs baseline: 1.0963x; 1.0963x over previous
//
#include <hip/hip_runtime.h>
#include <hip/hip_bf16.h>

#define H 768
#define NH 12
#define DH 64
#define NNODES 2048
#define NEDGES 131072

typedef __bf16 bf16x8 __attribute__((ext_vector_type(8)));
typedef float floatx4 __attribute__((ext_vector_type(4)));

// direct global->LDS DMA, 16B per lane (dest must be wave-uniform base + lane*16)
#define GLOAD_LDS16(gptr, ldsptr)                                                        \
  __builtin_amdgcn_global_load_lds((const __attribute__((address_space(1))) void*)(gptr), \
                                   (__attribute__((address_space(3))) void*)(ldsptr),     \
                                   16, 0, 0)

__device__ __forceinline__ unsigned short f2bf(float x) {
  union { __hip_bfloat16 h; unsigned short u; } cv;
  cv.h = __float2bfloat16(x);
  return cv.u;
}

// ---------------- fp32 -> bf16 conversion (vectorized x4) + hist zero -------
__global__ __launch_bounds__(256)
void convert_kernel(const float* __restrict__ hs,
                    const float* __restrict__ Wq,
                    const float* __restrict__ Wk,
                    const float* __restrict__ Wv,
                    __hip_bfloat16* __restrict__ hsb,
                    __hip_bfloat16* __restrict__ wb,
                    int* __restrict__ hist) {
  int i = blockIdx.x * 256 + threadIdx.x;
  const int n_hs4 = NNODES * H / 4;   // 393216
  const int n_w4  = H * H / 4;        // 147456
  if (i < n_hs4) {
    float4 v = ((const float4*)hs)[i];
    ((ushort4*)hsb)[i] = make_ushort4(f2bf(v.x), f2bf(v.y), f2bf(v.z), f2bf(v.w));
    return;
  }
  int j = i - n_hs4;
  if (j < 3 * n_w4) {
    const float* src = (j < n_w4) ? Wq : (j < 2 * n_w4 ? Wk : Wv);
    float4 v = ((const float4*)src)[j % n_w4];
    ((ushort4*)wb)[j] = make_ushort4(f2bf(v.x), f2bf(v.y), f2bf(v.z), f2bf(v.w));
    return;
  }
  int z = j - 3 * n_w4;
  if (z < NNODES / 4) {               // 512 int4 = 2048 ints
    ((int4*)hist)[z] = make_int4(0, 0, 0, 0);
  }
}

// ---------------- QKV projection GEMM: C = A * W^T + bias -------------------
__global__ __launch_bounds__(256)
void qkv_gemm(const __hip_bfloat16* __restrict__ A,
              const __hip_bfloat16* __restrict__ Wb,
              const float* __restrict__ b0,
              const float* __restrict__ b1,
              const float* __restrict__ b2,
              float* __restrict__ out) {
  __shared__ __hip_bfloat16 As[128][32];
  __shared__ __hip_bfloat16 Bs[128][32];

  const int t    = threadIdx.x;
  const int wave = t >> 6;
  const int lane = t & 63;
  const int bm   = blockIdx.x * 128;
  const int bn   = blockIdx.y * 128;
  const int mat  = blockIdx.z;

  const __hip_bfloat16* B = Wb + (size_t)mat * H * H;
  const float* bias = (mat == 0) ? b0 : ((mat == 1) ? b1 : b2);
  float* C = out + (size_t)mat * NNODES * H;

  const int wm = (wave & 1) * 64;
  const int wn = (wave >> 1) * 64;
  const int lr = lane & 15;
  const int lq = lane >> 4;

  floatx4 acc[4][4] = {};

  const int ar = t >> 2;
  const int ac = (t & 3) * 8;
  __hip_bfloat16* AsF = &As[0][0];
  __hip_bfloat16* BsF = &Bs[0][0];

  for (int kt = 0; kt < H; kt += 32) {
    GLOAD_LDS16(A + (size_t)(bm + ar) * H + kt + ac,      AsF + t * 8);
    GLOAD_LDS16(A + (size_t)(bm + 64 + ar) * H + kt + ac, AsF + 64 * 32 + t * 8);
    GLOAD_LDS16(B + (size_t)(bn + ar) * H + kt + ac,      BsF + t * 8);
    GLOAD_LDS16(B + (size_t)(bn + 64 + ar) * H + kt + ac, BsF + 64 * 32 + t * 8);
    __syncthreads();

    bf16x8 af[4], bfr[4];
#pragma unroll
    for (int i = 0; i < 4; i++)
      af[i] = *(const bf16x8*)&As[wm + i * 16 + lr][lq * 8];
#pragma unroll
    for (int i = 0; i < 4; i++)
      bfr[i] = *(const bf16x8*)&Bs[wn + i * 16 + lr][lq * 8];
#pragma unroll
    for (int mi = 0; mi < 4; mi++)
#pragma unroll
      for (int ni = 0; ni < 4; ni++)
        acc[mi][ni] = __builtin_amdgcn_mfma_f32_16x16x32_bf16(
            af[mi], bfr[ni], acc[mi][ni], 0, 0, 0);
    __syncthreads();
  }

#pragma unroll
  for (int ni = 0; ni < 4; ni++) {
    int col = bn + wn + ni * 16 + lr;
    float bv = bias[col];
#pragma unroll
    for (int mi = 0; mi < 4; mi++) {
#pragma unroll
      for (int r = 0; r < 4; r++) {
        int row = bm + wm + mi * 16 + lq * 4 + r;
        C[(size_t)row * H + col] = acc[mi][ni][r] + bv;
      }
    }
  }
}

// ---------------- counting sort by tgt: histogram ---------------------------
__global__ __launch_bounds__(256)
void hist_kernel(const int* __restrict__ etgt, int* __restrict__ hist) {
  int e = blockIdx.x * 256 + threadIdx.x;
  atomicAdd(&hist[etgt[e]], 1);
}

// ---------------- counting sort: exclusive prefix sum (1 block) -------------
__global__ __launch_bounds__(256)
void scan_kernel(const int* __restrict__ hist, int* __restrict__ rowptr,
                 int* __restrict__ cursor) {
  __shared__ int part[256];
  int t = threadIdx.x;
  int loc[8];
  int s = 0;
#pragma unroll
  for (int k = 0; k < 8; k++) { loc[k] = s; s += hist[t * 8 + k]; }
  part[t] = s;
  __syncthreads();
  for (int off = 1; off < 256; off <<= 1) {
    int v = (t >= off) ? part[t - off] : 0;
    __syncthreads();
    if (t >= off) part[t] += v;
    __syncthreads();
  }
  int pre = part[t] - s;   // exclusive prefix of this thread's 8-chunk
#pragma unroll
  for (int k = 0; k < 8; k++) {
    rowptr[t * 8 + k] = pre + loc[k];
    cursor[t * 8 + k] = pre + loc[k];
  }
  if (t == 255) rowptr[NNODES] = part[255];
}

// ---------------- counting sort: scatter ------------------------------------
__global__ __launch_bounds__(256)
void scatter_kernel(const int* __restrict__ esrc, const int* __restrict__ etgt,
                    const int* __restrict__ epos,
                    int* __restrict__ cursor,
                    int* __restrict__ src_s, int* __restrict__ pos_s,
                    int* __restrict__ einv) {
  int e = blockIdx.x * 256 + threadIdx.x;
  int tgt = etgt[e];
  int slot = atomicAdd(&cursor[tgt], 1);
  src_s[slot] = esrc[e];
  pos_s[slot] = epos[e];
  einv[e] = slot;
}

// ---------------- scores: one block per target node, NO atomics -------------
// Q row + relk staged in LDS; denom accumulated in registers -> plain store.
__global__ __launch_bounds__(256)
void scores3_kernel(const float* __restrict__ Q, const float* __restrict__ K,
                    const float* __restrict__ relk,
                    const int* __restrict__ rowptr,
                    const int* __restrict__ src_s, const int* __restrict__ pos_s,
                    float* __restrict__ scores_s, float* __restrict__ denom) {
  const int t    = blockIdx.x;
  const int tid  = threadIdx.x;
  const int wave = tid >> 6;
  const int lane = tid & 63;
  const int g    = lane >> 4;
  const int off  = (lane & 15) * 4;

  __shared__ float Qs[H];            // 3 KB
  __shared__ float Rk[16 * DH];      // 4 KB
  __shared__ float dpart[4][NH];

  if (tid < 192)
    *(float4*)&Qs[tid * 4] = *(const float4*)(Q + (size_t)t * H + tid * 4);
  *(float4*)&Rk[tid * 4] = *(const float4*)(relk + tid * 4);
  __syncthreads();

  const int beg = rowptr[t], end = rowptr[t + 1];
  float dacc0 = 0.f, dacc1 = 0.f, dacc2 = 0.f;

  for (int i = beg + wave; i < end; i += 4) {
    const int src = src_s[i];
    const int pos = pos_s[i];
    const float* Kp = K + (size_t)src * H;
    const float4 r4 = *(const float4*)&Rk[pos * DH + off];
    float s[3];
#pragma unroll
    for (int c = 0; c < 3; c++) {
      float4 k4 = *(const float4*)(Kp + c * 256 + lane * 4);
      float4 q4 = *(const float4*)&Qs[c * 256 + lane * 4];
      s[c] = q4.x * (k4.x + r4.x) + q4.y * (k4.y + r4.y) +
             q4.z * (k4.z + r4.z) + q4.w * (k4.w + r4.w);
    }
#pragma unroll
    for (int m = 1; m < 16; m <<= 1) {
      s[0] += __shfl_xor(s[0], m);
      s[1] += __shfl_xor(s[1], m);
      s[2] += __shfl_xor(s[2], m);
    }
    if ((lane & 15) == 0) {
      float sc0 = __expf(s[0] * 0.125f);
      float sc1 = __expf(s[1] * 0.125f);
      float sc2 = __expf(s[2] * 0.125f);
      scores_s[(size_t)i * NH + g]     = sc0;
      scores_s[(size_t)i * NH + 4 + g] = sc1;
      scores_s[(size_t)i * NH + 8 + g] = sc2;
      dacc0 += sc0; dacc1 += sc1; dacc2 += sc2;
    }
  }

  if ((lane & 15) == 0) {
    dpart[wave][g]     = dacc0;
    dpart[wave][4 + g] = dacc1;
    dpart[wave][8 + g] = dacc2;
  }
  __syncthreads();
  if (tid < NH) {
    denom[(size_t)t * NH + tid] =
        dpart[0][tid] + dpart[1][tid] + dpart[2][tid] + dpart[3][tid];
  }
}

// ---------------- per-edge weighted values (original edge order) ------------
__global__ __launch_bounds__(256)
void weighted_kernel(const float* __restrict__ V, const float* __restrict__ relv,
                     const int* __restrict__ esrc, const int* __restrict__ etgt,
                     const int* __restrict__ epos,
                     const int* __restrict__ einv,
                     const float* __restrict__ scores_s,
                     const float* __restrict__ denom,
                     float* __restrict__ out) {
  const int wave = threadIdx.x >> 6;
  const int lane = threadIdx.x & 63;
  const int e = blockIdx.x * 4 + wave;
  const int src = esrc[e], tgt = etgt[e], pos = epos[e];
  const int sidx = einv[e];
  const int g = lane >> 4;
  const int off = (lane & 15) * 4;

  const float4 r4 = *(const float4*)(relv + pos * DH + off);
#pragma unroll
  for (int c = 0; c < 3; c++) {
    int h = c * 4 + g;
    float a = scores_s[(size_t)sidx * NH + h] / denom[(size_t)tgt * NH + h];
    float4 v4 = *(const float4*)(V + (size_t)src * H + c * 256 + lane * 4);
    floatx4 o;
    o.x = (v4.x + r4.x) * a;
    o.y = (v4.y + r4.y) * a;
    o.z = (v4.z + r4.z) * a;
    o.w = (v4.w + r4.w) * a;
    __builtin_nontemporal_store(o, (floatx4*)(out + (size_t)e * H + c * 256 + lane * 4));
  }
}

extern "C" void kernel_launch(void* const* d_in, const int* in_sizes, int n_in,
                              void* d_out, int out_size, void* d_ws, size_t ws_size,
                              hipStream_t stream) {
  const float* hs   = (const float*)d_in[0];
  const float* Wq   = (const float*)d_in[1];
  const float* bq   = (const float*)d_in[2];
  const float* Wk   = (const float*)d_in[3];
  const float* bk   = (const float*)d_in[4];
  const float* Wv   = (const float*)d_in[5];
  const float* bv   = (const float*)d_in[6];
  const float* relk = (const float*)d_in[7];
  const float* relv = (const float*)d_in[8];
  const int* esrc   = (const int*)d_in[9];
  const int* etgt   = (const int*)d_in[10];
  const int* epos   = (const int*)d_in[12];
  float* out = (float*)d_out;

  char* ws = (char*)d_ws;
  __hip_bfloat16* hsb = (__hip_bfloat16*)ws;                 //  3,145,728 B
  __hip_bfloat16* wb  = (__hip_bfloat16*)(ws + 3145728);     //  3,538,944 B
  float* qkv      = (float*)(ws + 6684672);                  // 18,874,368 B
  float* scores_s = (float*)(ws + 25559040);                 //  6,291,456 B
  float* denom    = (float*)(ws + 31850496);                 //     98,304 B
  int* hist       = (int*)(ws + 31948800);                   //      8,192 B
  int* rowptr     = (int*)(ws + 31956992);                   //      8,208 B
  int* cursor     = (int*)(ws + 31965200);                   //      8,192 B
  // sort arrays overlap hsb (hsb is dead after qkv_gemm; stream-ordered):
  int* src_s = (int*)ws;                                     //    524,288 B
  int* pos_s = (int*)(ws + 524288);                          //    524,288 B
  int* einv  = (int*)(ws + 1048576);                         //    524,288 B

  // 1) convert hs + weights to bf16; zero hist
  //    threads = 393216 + 442368 + 512 = 836096 = 3266 * 256
  convert_kernel<<<3266, 256, 0, stream>>>(hs, Wq, Wk, Wv, hsb, wb, hist);

  // 2) QKV projection (bf16 MFMA, global_load_lds staging)
  dim3 grid_gemm(16, 6, 3);
  qkv_gemm<<<grid_gemm, 256, 0, stream>>>(hsb, wb, bq, bk, bv, qkv);

  const float* Qp = qkv;
  const float* Kp = qkv + (size_t)NNODES * H;
  const float* Vp = qkv + (size_t)2 * NNODES * H;

  // 3-5) counting sort of edges by tgt -> CSR + inverse perm
  hist_kernel<<<NEDGES / 256, 256, 0, stream>>>(etgt, hist);
  scan_kernel<<<1, 256, 0, stream>>>(hist, rowptr, cursor);
  scatter_kernel<<<NEDGES / 256, 256, 0, stream>>>(esrc, etgt, epos, cursor,
                                                   src_s, pos_s, einv);

  // 6) scores per target node: LDS Q row, register denom, zero atomics
  scores3_kernel<<<NNODES, 256, 0, stream>>>(Qp, Kp, relk, rowptr, src_s, pos_s,
                                             scores_s, denom);

  // 7) per-edge weighted values -> out (nontemporal, sequential writes)
  weighted_kernel<<<NEDGES / 4, 256, 0, stream>>>(Vp, relv, esrc, etgt, epos,
                                                  einv, scores_s, denom, out);
}

// Round 5
// 529.801 us; speedup vs baseline: 1.1118x; 1.0141x over previous
//
#include <hip/hip_runtime.h>
#include <hip/hip_bf16.h>

#define H 768
#define NH 12
#define DH 64
#define NNODES 2048
#define NEDGES 131072

typedef __bf16 bf16x8 __attribute__((ext_vector_type(8)));
typedef float floatx4 __attribute__((ext_vector_type(4)));

// direct global->LDS DMA, 16B per lane (dest must be wave-uniform base + lane*16)
#define GLOAD_LDS16(gptr, ldsptr)                                                        \
  __builtin_amdgcn_global_load_lds((const __attribute__((address_space(1))) void*)(gptr), \
                                   (__attribute__((address_space(3))) void*)(ldsptr),     \
                                   16, 0, 0)

__device__ __forceinline__ unsigned short f2bf(float x) {
  union { __hip_bfloat16 h; unsigned short u; } cv;
  cv.h = __float2bfloat16(x);
  return cv.u;
}

// exact bf16 -> fp32 (bit shift)
__device__ __forceinline__ float bfu2f(unsigned short u) {
  union { float f; unsigned int i; } c;
  c.i = ((unsigned int)u) << 16;
  return c.f;
}

// ---------------- fp32 -> bf16 conversion (vectorized x4) + hist zero -------
__global__ __launch_bounds__(256)
void convert_kernel(const float* __restrict__ hs,
                    const float* __restrict__ Wq,
                    const float* __restrict__ Wk,
                    const float* __restrict__ Wv,
                    __hip_bfloat16* __restrict__ hsb,
                    __hip_bfloat16* __restrict__ wb,
                    int* __restrict__ hist) {
  int i = blockIdx.x * 256 + threadIdx.x;
  const int n_hs4 = NNODES * H / 4;   // 393216
  const int n_w4  = H * H / 4;        // 147456
  if (i < n_hs4) {
    float4 v = ((const float4*)hs)[i];
    ((ushort4*)hsb)[i] = make_ushort4(f2bf(v.x), f2bf(v.y), f2bf(v.z), f2bf(v.w));
    return;
  }
  int j = i - n_hs4;
  if (j < 3 * n_w4) {
    const float* src = (j < n_w4) ? Wq : (j < 2 * n_w4 ? Wk : Wv);
    float4 v = ((const float4*)src)[j % n_w4];
    ((ushort4*)wb)[j] = make_ushort4(f2bf(v.x), f2bf(v.y), f2bf(v.z), f2bf(v.w));
    return;
  }
  int z = j - 3 * n_w4;
  if (z < NNODES / 4) {               // 512 int4 = 2048 ints
    ((int4*)hist)[z] = make_int4(0, 0, 0, 0);
  }
}

// ---------------- QKV projection GEMM: C = A * W^T + bias -------------------
// 64x64 tiles, grid (32,12,3) = 1152 blocks (4.5/CU; old 288-block grid had a
// 2.0x occupancy tail: 32 CUs ran 2 serial blocks while 224 ran 1).
// mat==1 (K) is emitted as bf16 directly (halves scores-phase gather traffic).
__global__ __launch_bounds__(256)
void qkv_gemm(const __hip_bfloat16* __restrict__ A,
              const __hip_bfloat16* __restrict__ Wb,
              const float* __restrict__ b0,
              const float* __restrict__ b1,
              const float* __restrict__ b2,
              float* __restrict__ out,
              __hip_bfloat16* __restrict__ kb) {
  __shared__ __hip_bfloat16 As[64][32];
  __shared__ __hip_bfloat16 Bs[64][32];

  const int t    = threadIdx.x;
  const int wave = t >> 6;
  const int lane = t & 63;
  const int bm   = blockIdx.x * 64;
  const int bn   = blockIdx.y * 64;
  const int mat  = blockIdx.z;

  const __hip_bfloat16* B = Wb + (size_t)mat * H * H;
  const float* bias = (mat == 0) ? b0 : ((mat == 1) ? b1 : b2);

  const int wm = (wave & 1) * 32;
  const int wn = (wave >> 1) * 32;
  const int lr = lane & 15;
  const int lq = lane >> 4;

  floatx4 acc[2][2] = {};

  const int ar = t >> 2;         // 0..63 staging row
  const int ac = (t & 3) * 8;    // k-offset
  __hip_bfloat16* AsF = &As[0][0];
  __hip_bfloat16* BsF = &Bs[0][0];

  for (int kt = 0; kt < H; kt += 32) {
    GLOAD_LDS16(A + (size_t)(bm + ar) * H + kt + ac, AsF + t * 8);
    GLOAD_LDS16(B + (size_t)(bn + ar) * H + kt + ac, BsF + t * 8);
    __syncthreads();

    bf16x8 af[2], bfr[2];
#pragma unroll
    for (int i = 0; i < 2; i++)
      af[i] = *(const bf16x8*)&As[wm + i * 16 + lr][lq * 8];
#pragma unroll
    for (int i = 0; i < 2; i++)
      bfr[i] = *(const bf16x8*)&Bs[wn + i * 16 + lr][lq * 8];
#pragma unroll
    for (int mi = 0; mi < 2; mi++)
#pragma unroll
      for (int ni = 0; ni < 2; ni++)
        acc[mi][ni] = __builtin_amdgcn_mfma_f32_16x16x32_bf16(
            af[mi], bfr[ni], acc[mi][ni], 0, 0, 0);
    __syncthreads();
  }

  // epilogue: C/D layout col = lane&15, row = (lane>>4)*4 + reg  [m89-verified]
  if (mat == 1) {
#pragma unroll
    for (int ni = 0; ni < 2; ni++) {
      int col = bn + wn + ni * 16 + lr;
      float bv = bias[col];
#pragma unroll
      for (int mi = 0; mi < 2; mi++) {
#pragma unroll
        for (int r = 0; r < 4; r++) {
          int row = bm + wm + mi * 16 + lq * 4 + r;
          kb[(size_t)row * H + col] = __float2bfloat16(acc[mi][ni][r] + bv);
        }
      }
    }
  } else {
    float* C = out + (size_t)mat * NNODES * H;
#pragma unroll
    for (int ni = 0; ni < 2; ni++) {
      int col = bn + wn + ni * 16 + lr;
      float bv = bias[col];
#pragma unroll
      for (int mi = 0; mi < 2; mi++) {
#pragma unroll
        for (int r = 0; r < 4; r++) {
          int row = bm + wm + mi * 16 + lq * 4 + r;
          C[(size_t)row * H + col] = acc[mi][ni][r] + bv;
        }
      }
    }
  }
}

// ---------------- counting sort by tgt: histogram ---------------------------
__global__ __launch_bounds__(256)
void hist_kernel(const int* __restrict__ etgt, int* __restrict__ hist) {
  int e = blockIdx.x * 256 + threadIdx.x;
  atomicAdd(&hist[etgt[e]], 1);
}

// ---------------- counting sort: exclusive prefix sum (1 block) -------------
__global__ __launch_bounds__(256)
void scan_kernel(const int* __restrict__ hist, int* __restrict__ rowptr,
                 int* __restrict__ cursor) {
  __shared__ int part[256];
  int t = threadIdx.x;
  int loc[8];
  int s = 0;
#pragma unroll
  for (int k = 0; k < 8; k++) { loc[k] = s; s += hist[t * 8 + k]; }
  part[t] = s;
  __syncthreads();
  for (int off = 1; off < 256; off <<= 1) {
    int v = (t >= off) ? part[t - off] : 0;
    __syncthreads();
    if (t >= off) part[t] += v;
    __syncthreads();
  }
  int pre = part[t] - s;
#pragma unroll
  for (int k = 0; k < 8; k++) {
    rowptr[t * 8 + k] = pre + loc[k];
    cursor[t * 8 + k] = pre + loc[k];
  }
  if (t == 255) rowptr[NNODES] = part[255];
}

// ---------------- counting sort: scatter ------------------------------------
__global__ __launch_bounds__(256)
void scatter_kernel(const int* __restrict__ esrc, const int* __restrict__ etgt,
                    const int* __restrict__ epos,
                    int* __restrict__ cursor,
                    int* __restrict__ src_s, int* __restrict__ pos_s,
                    int* __restrict__ einv) {
  int e = blockIdx.x * 256 + threadIdx.x;
  int tgt = etgt[e];
  int slot = atomicAdd(&cursor[tgt], 1);
  src_s[slot] = esrc[e];
  pos_s[slot] = epos[e];
  einv[e] = slot;
}

// ---------------- scores: one block per target node, bf16 K gather ----------
__global__ __launch_bounds__(256)
void scores3_kernel(const float* __restrict__ Q,
                    const __hip_bfloat16* __restrict__ Kb,
                    const float* __restrict__ relk,
                    const int* __restrict__ rowptr,
                    const int* __restrict__ src_s, const int* __restrict__ pos_s,
                    float* __restrict__ scores_s, float* __restrict__ denom) {
  const int t    = blockIdx.x;
  const int tid  = threadIdx.x;
  const int wave = tid >> 6;
  const int lane = tid & 63;
  const int g    = lane >> 4;
  const int off  = (lane & 15) * 4;

  __shared__ float Qs[H];            // 3 KB
  __shared__ float Rk[16 * DH];      // 4 KB
  __shared__ float dpart[4][NH];

  if (tid < 192)
    *(float4*)&Qs[tid * 4] = *(const float4*)(Q + (size_t)t * H + tid * 4);
  *(float4*)&Rk[tid * 4] = *(const float4*)(relk + tid * 4);
  __syncthreads();

  const int beg = rowptr[t], end = rowptr[t + 1];
  float dacc0 = 0.f, dacc1 = 0.f, dacc2 = 0.f;

  for (int i = beg + wave; i < end; i += 4) {
    const int src = src_s[i];
    const int pos = pos_s[i];
    const unsigned short* Kp = (const unsigned short*)(Kb + (size_t)src * H);
    const float4 r4 = *(const float4*)&Rk[pos * DH + off];
    float s[3];
#pragma unroll
    for (int c = 0; c < 3; c++) {
      ushort4 ku = *(const ushort4*)(Kp + c * 256 + lane * 4);
      float4 q4 = *(const float4*)&Qs[c * 256 + lane * 4];
      s[c] = q4.x * (bfu2f(ku.x) + r4.x) + q4.y * (bfu2f(ku.y) + r4.y) +
             q4.z * (bfu2f(ku.z) + r4.z) + q4.w * (bfu2f(ku.w) + r4.w);
    }
#pragma unroll
    for (int m = 1; m < 16; m <<= 1) {
      s[0] += __shfl_xor(s[0], m);
      s[1] += __shfl_xor(s[1], m);
      s[2] += __shfl_xor(s[2], m);
    }
    if ((lane & 15) == 0) {
      float sc0 = __expf(s[0] * 0.125f);
      float sc1 = __expf(s[1] * 0.125f);
      float sc2 = __expf(s[2] * 0.125f);
      scores_s[(size_t)i * NH + g]     = sc0;
      scores_s[(size_t)i * NH + 4 + g] = sc1;
      scores_s[(size_t)i * NH + 8 + g] = sc2;
      dacc0 += sc0; dacc1 += sc1; dacc2 += sc2;
    }
  }

  if ((lane & 15) == 0) {
    dpart[wave][g]     = dacc0;
    dpart[wave][4 + g] = dacc1;
    dpart[wave][8 + g] = dacc2;
  }
  __syncthreads();
  if (tid < NH) {
    denom[(size_t)t * NH + tid] =
        dpart[0][tid] + dpart[1][tid] + dpart[2][tid] + dpart[3][tid];
  }
}

// ---------------- per-edge weighted values (original edge order) ------------
__global__ __launch_bounds__(256)
void weighted_kernel(const float* __restrict__ V, const float* __restrict__ relv,
                     const int* __restrict__ esrc, const int* __restrict__ etgt,
                     const int* __restrict__ epos,
                     const int* __restrict__ einv,
                     const float* __restrict__ scores_s,
                     const float* __restrict__ denom,
                     float* __restrict__ out) {
  const int wave = threadIdx.x >> 6;
  const int lane = threadIdx.x & 63;
  const int e = blockIdx.x * 4 + wave;
  const int src = esrc[e], tgt = etgt[e], pos = epos[e];
  const int sidx = einv[e];
  const int g = lane >> 4;
  const int off = (lane & 15) * 4;

  const float4 r4 = *(const float4*)(relv + pos * DH + off);
#pragma unroll
  for (int c = 0; c < 3; c++) {
    int h = c * 4 + g;
    float a = scores_s[(size_t)sidx * NH + h] / denom[(size_t)tgt * NH + h];
    float4 v4 = *(const float4*)(V + (size_t)src * H + c * 256 + lane * 4);
    floatx4 o;
    o.x = (v4.x + r4.x) * a;
    o.y = (v4.y + r4.y) * a;
    o.z = (v4.z + r4.z) * a;
    o.w = (v4.w + r4.w) * a;
    __builtin_nontemporal_store(o, (floatx4*)(out + (size_t)e * H + c * 256 + lane * 4));
  }
}

extern "C" void kernel_launch(void* const* d_in, const int* in_sizes, int n_in,
                              void* d_out, int out_size, void* d_ws, size_t ws_size,
                              hipStream_t stream) {
  const float* hs   = (const float*)d_in[0];
  const float* Wq   = (const float*)d_in[1];
  const float* bq   = (const float*)d_in[2];
  const float* Wk   = (const float*)d_in[3];
  const float* bk   = (const float*)d_in[4];
  const float* Wv   = (const float*)d_in[5];
  const float* bv   = (const float*)d_in[6];
  const float* relk = (const float*)d_in[7];
  const float* relv = (const float*)d_in[8];
  const int* esrc   = (const int*)d_in[9];
  const int* etgt   = (const int*)d_in[10];
  const int* epos   = (const int*)d_in[12];
  float* out = (float*)d_out;

  char* ws = (char*)d_ws;
  __hip_bfloat16* hsb = (__hip_bfloat16*)ws;                 //  3,145,728 B
  __hip_bfloat16* wb  = (__hip_bfloat16*)(ws + 3145728);     //  3,538,944 B
  float* qkv      = (float*)(ws + 6684672);                  // 18,874,368 B (K slot unused)
  float* scores_s = (float*)(ws + 25559040);                 //  6,291,456 B
  float* denom    = (float*)(ws + 31850496);                 //     98,304 B
  int* hist       = (int*)(ws + 31948800);                   //      8,192 B
  int* rowptr     = (int*)(ws + 31956992);                   //      8,208 B
  int* cursor     = (int*)(ws + 31965200);                   //      8,192 B
  __hip_bfloat16* kb = (__hip_bfloat16*)(ws + 31973392);     //  3,145,728 B (bf16 K)
  // sort arrays overlap hsb (hsb dead after qkv_gemm; stream-ordered):
  int* src_s = (int*)ws;                                     //    524,288 B
  int* pos_s = (int*)(ws + 524288);                          //    524,288 B
  int* einv  = (int*)(ws + 1048576);                         //    524,288 B

  // 1) convert hs + weights to bf16; zero hist
  convert_kernel<<<3266, 256, 0, stream>>>(hs, Wq, Wk, Wv, hsb, wb, hist);

  // 2) QKV projection: 64x64 tiles, 1152 blocks; K emitted as bf16
  dim3 grid_gemm(32, 12, 3);
  qkv_gemm<<<grid_gemm, 256, 0, stream>>>(hsb, wb, bq, bk, bv, qkv, kb);

  const float* Qp = qkv;
  const float* Vp = qkv + (size_t)2 * NNODES * H;

  // 3-5) counting sort of edges by tgt -> CSR + inverse perm
  hist_kernel<<<NEDGES / 256, 256, 0, stream>>>(etgt, hist);
  scan_kernel<<<1, 256, 0, stream>>>(hist, rowptr, cursor);
  scatter_kernel<<<NEDGES / 256, 256, 0, stream>>>(esrc, etgt, epos, cursor,
                                                   src_s, pos_s, einv);

  // 6) scores per target node: LDS Q row, bf16 K gather, register denom
  scores3_kernel<<<NNODES, 256, 0, stream>>>(Qp, kb, relk, rowptr, src_s, pos_s,
                                             scores_s, denom);

  // 7) per-edge weighted values -> out (nontemporal, sequential writes)
  weighted_kernel<<<NEDGES / 4, 256, 0, stream>>>(Vp, relv, esrc, etgt, epos,
                                                  einv, scores_s, denom, out);
}

// Round 6
// 526.265 us; speedup vs baseline: 1.1192x; 1.0067x over previous
//
#include <hip/hip_runtime.h>
#include <hip/hip_bf16.h>

#define H 768
#define NH 12
#define DH 64
#define NNODES 2048
#define NEDGES 131072

typedef __bf16 bf16x8 __attribute__((ext_vector_type(8)));
typedef float floatx4 __attribute__((ext_vector_type(4)));

// direct global->LDS DMA, 16B per lane (dest must be wave-uniform base + lane*16)
#define GLOAD_LDS16(gptr, ldsptr)                                                        \
  __builtin_amdgcn_global_load_lds((const __attribute__((address_space(1))) void*)(gptr), \
                                   (__attribute__((address_space(3))) void*)(ldsptr),     \
                                   16, 0, 0)

__device__ __forceinline__ unsigned short f2bf(float x) {
  union { __hip_bfloat16 h; unsigned short u; } cv;
  cv.h = __float2bfloat16(x);
  return cv.u;
}

// exact bf16 -> fp32 (bit shift)
__device__ __forceinline__ float bfu2f(unsigned short u) {
  union { float f; unsigned int i; } c;
  c.i = ((unsigned int)u) << 16;
  return c.f;
}

// ---------------- fp32 -> bf16 conversion (vectorized x4) + hist zero -------
__global__ __launch_bounds__(256)
void convert_kernel(const float* __restrict__ hs,
                    const float* __restrict__ Wq,
                    const float* __restrict__ Wk,
                    const float* __restrict__ Wv,
                    __hip_bfloat16* __restrict__ hsb,
                    __hip_bfloat16* __restrict__ wb,
                    int* __restrict__ hist) {
  int i = blockIdx.x * 256 + threadIdx.x;
  const int n_hs4 = NNODES * H / 4;   // 393216
  const int n_w4  = H * H / 4;        // 147456
  if (i < n_hs4) {
    float4 v = ((const float4*)hs)[i];
    ((ushort4*)hsb)[i] = make_ushort4(f2bf(v.x), f2bf(v.y), f2bf(v.z), f2bf(v.w));
    return;
  }
  int j = i - n_hs4;
  if (j < 3 * n_w4) {
    const float* src = (j < n_w4) ? Wq : (j < 2 * n_w4 ? Wk : Wv);
    float4 v = ((const float4*)src)[j % n_w4];
    ((ushort4*)wb)[j] = make_ushort4(f2bf(v.x), f2bf(v.y), f2bf(v.z), f2bf(v.w));
    return;
  }
  int z = j - 3 * n_w4;
  if (z < NNODES / 4) {               // 512 int4 = 2048 ints
    ((int4*)hist)[z] = make_int4(0, 0, 0, 0);
  }
}

// ---------------- QKV projection GEMM: C = A * W^T + bias -------------------
// 64x64 tiles, grid (32,12,3) = 1152 blocks.
// mat==1 (K) emitted as bf16 (halves scores-phase gather traffic).
__global__ __launch_bounds__(256)
void qkv_gemm(const __hip_bfloat16* __restrict__ A,
              const __hip_bfloat16* __restrict__ Wb,
              const float* __restrict__ b0,
              const float* __restrict__ b1,
              const float* __restrict__ b2,
              float* __restrict__ out,
              __hip_bfloat16* __restrict__ kb) {
  __shared__ __hip_bfloat16 As[64][32];
  __shared__ __hip_bfloat16 Bs[64][32];

  const int t    = threadIdx.x;
  const int wave = t >> 6;
  const int lane = t & 63;
  const int bm   = blockIdx.x * 64;
  const int bn   = blockIdx.y * 64;
  const int mat  = blockIdx.z;

  const __hip_bfloat16* B = Wb + (size_t)mat * H * H;
  const float* bias = (mat == 0) ? b0 : ((mat == 1) ? b1 : b2);

  const int wm = (wave & 1) * 32;
  const int wn = (wave >> 1) * 32;
  const int lr = lane & 15;
  const int lq = lane >> 4;

  floatx4 acc[2][2] = {};

  const int ar = t >> 2;
  const int ac = (t & 3) * 8;
  __hip_bfloat16* AsF = &As[0][0];
  __hip_bfloat16* BsF = &Bs[0][0];

  for (int kt = 0; kt < H; kt += 32) {
    GLOAD_LDS16(A + (size_t)(bm + ar) * H + kt + ac, AsF + t * 8);
    GLOAD_LDS16(B + (size_t)(bn + ar) * H + kt + ac, BsF + t * 8);
    __syncthreads();

    bf16x8 af[2], bfr[2];
#pragma unroll
    for (int i = 0; i < 2; i++)
      af[i] = *(const bf16x8*)&As[wm + i * 16 + lr][lq * 8];
#pragma unroll
    for (int i = 0; i < 2; i++)
      bfr[i] = *(const bf16x8*)&Bs[wn + i * 16 + lr][lq * 8];
#pragma unroll
    for (int mi = 0; mi < 2; mi++)
#pragma unroll
      for (int ni = 0; ni < 2; ni++)
        acc[mi][ni] = __builtin_amdgcn_mfma_f32_16x16x32_bf16(
            af[mi], bfr[ni], acc[mi][ni], 0, 0, 0);
    __syncthreads();
  }

  // epilogue: C/D layout col = lane&15, row = (lane>>4)*4 + reg  [m89-verified]
  if (mat == 1) {
#pragma unroll
    for (int ni = 0; ni < 2; ni++) {
      int col = bn + wn + ni * 16 + lr;
      float bv = bias[col];
#pragma unroll
      for (int mi = 0; mi < 2; mi++) {
#pragma unroll
        for (int r = 0; r < 4; r++) {
          int row = bm + wm + mi * 16 + lq * 4 + r;
          kb[(size_t)row * H + col] = __float2bfloat16(acc[mi][ni][r] + bv);
        }
      }
    }
  } else {
    float* C = out + (size_t)mat * NNODES * H;
#pragma unroll
    for (int ni = 0; ni < 2; ni++) {
      int col = bn + wn + ni * 16 + lr;
      float bv = bias[col];
#pragma unroll
      for (int mi = 0; mi < 2; mi++) {
#pragma unroll
        for (int r = 0; r < 4; r++) {
          int row = bm + wm + mi * 16 + lq * 4 + r;
          C[(size_t)row * H + col] = acc[mi][ni][r] + bv;
        }
      }
    }
  }
}

// ---------------- counting sort by tgt: histogram ---------------------------
__global__ __launch_bounds__(256)
void hist_kernel(const int* __restrict__ etgt, int* __restrict__ hist) {
  int e = blockIdx.x * 256 + threadIdx.x;
  atomicAdd(&hist[etgt[e]], 1);
}

// ---------------- counting sort: exclusive prefix sum (1 block) -------------
__global__ __launch_bounds__(256)
void scan_kernel(const int* __restrict__ hist, int* __restrict__ rowptr,
                 int* __restrict__ cursor) {
  __shared__ int part[256];
  int t = threadIdx.x;
  int loc[8];
  int s = 0;
#pragma unroll
  for (int k = 0; k < 8; k++) { loc[k] = s; s += hist[t * 8 + k]; }
  part[t] = s;
  __syncthreads();
  for (int off = 1; off < 256; off <<= 1) {
    int v = (t >= off) ? part[t - off] : 0;
    __syncthreads();
    if (t >= off) part[t] += v;
    __syncthreads();
  }
  int pre = part[t] - s;
#pragma unroll
  for (int k = 0; k < 8; k++) {
    rowptr[t * 8 + k] = pre + loc[k];
    cursor[t * 8 + k] = pre + loc[k];
  }
  if (t == 255) rowptr[NNODES] = part[255];
}

// ---------------- counting sort: scatter (stores orig edge id) --------------
__global__ __launch_bounds__(256)
void scatter_kernel(const int* __restrict__ esrc, const int* __restrict__ etgt,
                    const int* __restrict__ epos,
                    int* __restrict__ cursor,
                    int* __restrict__ src_s, int* __restrict__ pos_s,
                    int* __restrict__ eorig) {
  int e = blockIdx.x * 256 + threadIdx.x;
  int tgt = etgt[e];
  int slot = atomicAdd(&cursor[tgt], 1);
  src_s[slot] = esrc[e];
  pos_s[slot] = epos[e];
  eorig[slot] = e;
}

// ---------------- fused edge phase: one block per target node ---------------
// pass1: scores (bf16 K gather) -> scores_s + in-LDS denom (zero atomics)
// pass2: attn = sc * (1/denom), V gather, nt-write out[eorig] (3KB contiguous)
__global__ __launch_bounds__(256)
void edge_fused_kernel(const float* __restrict__ Q,
                       const __hip_bfloat16* __restrict__ Kb,
                       const float* __restrict__ V,
                       const float* __restrict__ relk,
                       const float* __restrict__ relv,
                       const int* __restrict__ rowptr,
                       const int* __restrict__ src_s,
                       const int* __restrict__ pos_s,
                       const int* __restrict__ eorig,
                       float* __restrict__ scores_s,
                       float* __restrict__ out) {
  const int t    = blockIdx.x;
  const int tid  = threadIdx.x;
  const int wave = tid >> 6;
  const int lane = tid & 63;
  const int g    = lane >> 4;
  const int off  = (lane & 15) * 4;

  __shared__ float Qs[H];            // 3 KB
  __shared__ float Rs[16 * DH];      // 4 KB (relk in pass1, relv in pass2)
  __shared__ float dpart[4][NH];
  __shared__ float dinv[NH];

  if (tid < 192)
    *(float4*)&Qs[tid * 4] = *(const float4*)(Q + (size_t)t * H + tid * 4);
  *(float4*)&Rs[tid * 4] = *(const float4*)(relk + tid * 4);
  __syncthreads();

  const int beg = rowptr[t], end = rowptr[t + 1];
  float dacc0 = 0.f, dacc1 = 0.f, dacc2 = 0.f;

  // ---- pass 1: exp-scores + register denom ----
  for (int i = beg + wave; i < end; i += 4) {
    const int src = src_s[i];
    const int pos = pos_s[i];
    const unsigned short* Kp = (const unsigned short*)(Kb + (size_t)src * H);
    const float4 r4 = *(const float4*)&Rs[pos * DH + off];
    float s[3];
#pragma unroll
    for (int c = 0; c < 3; c++) {
      ushort4 ku = *(const ushort4*)(Kp + c * 256 + lane * 4);
      float4 q4 = *(const float4*)&Qs[c * 256 + lane * 4];
      s[c] = q4.x * (bfu2f(ku.x) + r4.x) + q4.y * (bfu2f(ku.y) + r4.y) +
             q4.z * (bfu2f(ku.z) + r4.z) + q4.w * (bfu2f(ku.w) + r4.w);
    }
#pragma unroll
    for (int m = 1; m < 16; m <<= 1) {
      s[0] += __shfl_xor(s[0], m);
      s[1] += __shfl_xor(s[1], m);
      s[2] += __shfl_xor(s[2], m);
    }
    if ((lane & 15) == 0) {
      float sc0 = __expf(s[0] * 0.125f);
      float sc1 = __expf(s[1] * 0.125f);
      float sc2 = __expf(s[2] * 0.125f);
      scores_s[(size_t)i * NH + g]     = sc0;
      scores_s[(size_t)i * NH + 4 + g] = sc1;
      scores_s[(size_t)i * NH + 8 + g] = sc2;
      dacc0 += sc0; dacc1 += sc1; dacc2 += sc2;
    }
  }

  if ((lane & 15) == 0) {
    dpart[wave][g]     = dacc0;
    dpart[wave][4 + g] = dacc1;
    dpart[wave][8 + g] = dacc2;
  }
  __syncthreads();   // also drains pass1 global stores (vmcnt(0) before barrier)

  // swap Rs to relv; compute 1/denom
  *(float4*)&Rs[tid * 4] = *(const float4*)(relv + tid * 4);
  if (tid < NH) {
    float den = dpart[0][tid] + dpart[1][tid] + dpart[2][tid] + dpart[3][tid];
    dinv[tid] = 1.0f / den;    // IEEE div (no fast-math): <=1 ulp vs per-edge div
  }
  __syncthreads();

  // ---- pass 2: normalize, V gather, nt-write ----
  for (int i = beg + wave; i < end; i += 4) {
    const int src = src_s[i];
    const int pos = pos_s[i];
    const int e   = eorig[i];
    const float4 r4 = *(const float4*)&Rs[pos * DH + off];
#pragma unroll
    for (int c = 0; c < 3; c++) {
      int h = c * 4 + g;
      float a = scores_s[(size_t)i * NH + h] * dinv[h];   // L2-hot, block-local
      float4 v4 = *(const float4*)(V + (size_t)src * H + c * 256 + lane * 4);
      floatx4 o;
      o.x = (v4.x + r4.x) * a;
      o.y = (v4.y + r4.y) * a;
      o.z = (v4.z + r4.z) * a;
      o.w = (v4.w + r4.w) * a;
      __builtin_nontemporal_store(
          o, (floatx4*)(out + (size_t)e * H + c * 256 + lane * 4));
    }
  }
}

extern "C" void kernel_launch(void* const* d_in, const int* in_sizes, int n_in,
                              void* d_out, int out_size, void* d_ws, size_t ws_size,
                              hipStream_t stream) {
  const float* hs   = (const float*)d_in[0];
  const float* Wq   = (const float*)d_in[1];
  const float* bq   = (const float*)d_in[2];
  const float* Wk   = (const float*)d_in[3];
  const float* bk   = (const float*)d_in[4];
  const float* Wv   = (const float*)d_in[5];
  const float* bv   = (const float*)d_in[6];
  const float* relk = (const float*)d_in[7];
  const float* relv = (const float*)d_in[8];
  const int* esrc   = (const int*)d_in[9];
  const int* etgt   = (const int*)d_in[10];
  const int* epos   = (const int*)d_in[12];
  float* out = (float*)d_out;

  char* ws = (char*)d_ws;
  __hip_bfloat16* hsb = (__hip_bfloat16*)ws;                 //  3,145,728 B
  __hip_bfloat16* wb  = (__hip_bfloat16*)(ws + 3145728);     //  3,538,944 B
  float* qkv      = (float*)(ws + 6684672);                  // 18,874,368 B (K slot unused)
  float* scores_s = (float*)(ws + 25559040);                 //  6,291,456 B
  int* hist       = (int*)(ws + 31948800);                   //      8,192 B
  int* rowptr     = (int*)(ws + 31956992);                   //      8,208 B
  int* cursor     = (int*)(ws + 31965200);                   //      8,192 B
  __hip_bfloat16* kb = (__hip_bfloat16*)(ws + 31973392);     //  3,145,728 B (bf16 K)
  // sort arrays overlap hsb (hsb dead after qkv_gemm; stream-ordered):
  int* src_s = (int*)ws;                                     //    524,288 B
  int* pos_s = (int*)(ws + 524288);                          //    524,288 B
  int* eorig = (int*)(ws + 1048576);                         //    524,288 B

  // 1) convert hs + weights to bf16; zero hist
  convert_kernel<<<3266, 256, 0, stream>>>(hs, Wq, Wk, Wv, hsb, wb, hist);

  // 2) QKV projection: 64x64 tiles; K emitted as bf16
  dim3 grid_gemm(32, 12, 3);
  qkv_gemm<<<grid_gemm, 256, 0, stream>>>(hsb, wb, bq, bk, bv, qkv, kb);

  const float* Qp = qkv;
  const float* Vp = qkv + (size_t)2 * NNODES * H;

  // 3-5) counting sort of edges by tgt -> CSR (+ orig edge id per slot)
  hist_kernel<<<NEDGES / 256, 256, 0, stream>>>(etgt, hist);
  scan_kernel<<<1, 256, 0, stream>>>(hist, rowptr, cursor);
  scatter_kernel<<<NEDGES / 256, 256, 0, stream>>>(esrc, etgt, epos, cursor,
                                                   src_s, pos_s, eorig);

  // 6) fused scores + normalize + weighted output (denom stays on-chip)
  edge_fused_kernel<<<NNODES, 256, 0, stream>>>(Qp, kb, Vp, relk, relv, rowptr,
                                                src_s, pos_s, eorig,
                                                scores_s, out);
}